// Round 2
// baseline (1066.616 us; speedup 1.0000x reference)
//
#include <hip/hip_runtime.h>
#include <hip/hip_bf16.h>

typedef __attribute__((ext_vector_type(8))) short short8;
typedef __attribute__((ext_vector_type(4))) float floatx4;
typedef __hip_bfloat16 bf16_t;

#define DD 768
#define SS 2048

__device__ __forceinline__ float sigmoid_f(float x) { return 1.f / (1.f + __expf(-x)); }

__device__ __forceinline__ void gl2lds16(const void* g, void* l) {
  __builtin_amdgcn_global_load_lds((const __attribute__((address_space(1))) void*)g,
                                   (__attribute__((address_space(3))) void*)l, 16, 0, 0);
}

// ---------------------------------------------------------------------------
// Generic bf16 MFMA GEMM:  out[M x N] (fp32, +bias) = A' (M x Kdim, bf16) @ Wt^T
//   Wt is [N][Kdim] bf16 (pre-transposed).
//   A' row r, col c (c in chunk j = c/768):  A[(min(r,M-1)+s_j) * lda + (c%768)]
//   BM=BN=128, BK=32 (divides 768 -> no chunk straddle), 256 thr (4 waves).
//   LDS swizzle: 16B-slot' = slot ^ ((row>>1)&3) on both staging source and read.
//   1D grid, column-panel-major + bijective XCD swizzle (each XCD owns a
//   contiguous run of column panels -> B panel cached in exactly one L2).
//   Epilogue: if gate_other, out = other[r][c] * sigmoid(acc+bias), else acc+bias.
// ---------------------------------------------------------------------------
__global__ __launch_bounds__(256) void gemm_shift(
    const bf16_t* __restrict__ A, int lda, int M, int nRowT,
    int s0, int s1, int s2,
    const bf16_t* __restrict__ Wt, int Kdim,
    const float* __restrict__ bias,
    float* __restrict__ out, int N,
    bf16_t* __restrict__ out_bf,
    const float* __restrict__ gate_other)
{
  __shared__ __attribute__((aligned(16))) unsigned char lds[16384]; // A: [0,8K) B: [8K,16K)
  const int tid  = threadIdx.x;
  const int wave = tid >> 6, lane = tid & 63;

  // bijective XCD swizzle (m204) then column-panel-major decode
  const int nwg = gridDim.x;
  const int q8 = nwg >> 3, r8 = nwg & 7;
  const int xcd = blockIdx.x & 7, lin = blockIdx.x >> 3;
  const int wgid = (xcd < r8 ? xcd * (q8 + 1) : r8 * (q8 + 1) + (xcd - r8) * q8) + lin;
  const int rowt = wgid % nRowT, colt = wgid / nRowT;

  const int rowbase = rowt * 128, colbase = colt * 128;
  const int wr = (wave >> 1) * 64, wc = (wave & 1) * 64;

  floatx4 acc[4][4] = {};
  const int nkt = Kdim >> 5;
  const int srow_t = tid >> 2;   // 0..63 (staging row within 64-row half)
  const int sslot  = tid & 3;    // 16B slot (physical)

  for (int kt = 0; kt < nkt; ++kt) {
    const int kbase = kt << 5;
    const int chunk = kbase / 768;
    const int shift = (chunk == 0) ? s0 : ((chunk == 1) ? s1 : s2);
    const int csrc  = kbase - chunk * 768;

    __syncthreads();  // all waves done reading LDS from prev iter
    #pragma unroll
    for (int p = 0; p < 2; ++p) {
      const int row = p * 64 + srow_t;
      const int k8  = sslot ^ ((row >> 1) & 3);   // pre-swizzled global source
      {
        const int gr = min(rowbase + row, M - 1) + shift;
        gl2lds16(A + (size_t)gr * lda + csrc + k8 * 8,
                 lds + p * 4096 + wave * 1024);
      }
      {
        const int gn = colbase + row;             // N always multiple of 128
        gl2lds16(Wt + (size_t)gn * Kdim + kbase + k8 * 8,
                 lds + 8192 + p * 4096 + wave * 1024);
      }
    }
    __syncthreads();  // compiler drains vmcnt before barrier -> LDS ready

    const int l15 = lane & 15, kq = lane >> 4;
    short8 af[4], bfr[4];
    #pragma unroll
    for (int i = 0; i < 4; ++i) {
      const int arow = wr + i * 16 + l15;
      const int as   = kq ^ ((arow >> 1) & 3);
      af[i] = *reinterpret_cast<const short8*>(&lds[arow * 64 + as * 16]);
      const int brow = wc + i * 16 + l15;
      const int bs   = kq ^ ((brow >> 1) & 3);
      bfr[i] = *reinterpret_cast<const short8*>(&lds[8192 + brow * 64 + bs * 16]);
    }
    #pragma unroll
    for (int i = 0; i < 4; ++i)
      #pragma unroll
      for (int j = 0; j < 4; ++j)
        acc[i][j] = __builtin_amdgcn_mfma_f32_16x16x32_bf16(af[i], bfr[j], acc[i][j], 0, 0, 0);
  }

  // epilogue: C/D layout col=lane&15, row=(lane>>4)*4+reg  [m89]
  const int l15 = lane & 15, hi = lane >> 4;
  #pragma unroll
  for (int i = 0; i < 4; ++i)
    #pragma unroll
    for (int j = 0; j < 4; ++j)
      #pragma unroll
      for (int rg = 0; rg < 4; ++rg) {
        const int r = rowbase + wr + i * 16 + hi * 4 + rg;
        const int c = colbase + wc + j * 16 + l15;
        if (r < M) {
          float v = acc[i][j][rg] + bias[c];
          if (gate_other) v = gate_other[(size_t)r * N + c] * sigmoid_f(v);
          out[(size_t)r * N + c] = v;
          if (out_bf) out_bf[(size_t)r * N + c] = __float2bfloat16(v);
        }
      }
}

// out[n*out_ld + k] = bf16(in[k*in_ld + n]); dims multiples of 32. block (32,8)
__global__ void transpose_cvt(const float* __restrict__ in, bf16_t* __restrict__ out,
                              int in_ld, int out_ld)
{
  __shared__ float tile[32][33];
  const int n0 = blockIdx.x * 32, k0 = blockIdx.y * 32;
  const int tx = threadIdx.x, ty = threadIdx.y;
  #pragma unroll
  for (int yy = ty; yy < 32; yy += 8)
    tile[yy][tx] = in[(size_t)(k0 + yy) * in_ld + n0 + tx];
  __syncthreads();
  #pragma unroll
  for (int yy = ty; yy < 32; yy += 8)
    out[(size_t)(n0 + yy) * out_ld + k0 + tx] = __float2bfloat16(tile[tx][yy]);
}

// wct[o*2304 + k*768 + i] = conv_w[o*2304 + i*3 + k]
__global__ void build_wct(const float* __restrict__ cw, bf16_t* __restrict__ wct) {
  const int idx = blockIdx.x * 256 + threadIdx.x;   // grid covers 768*2304 exactly
  const int o = idx / 2304, c = idx - o * 2304;
  const int k = c / 768, i = c - k * 768;
  wct[idx] = __float2bfloat16(cw[o * 2304 + i * 3 + k]);
}

__global__ void build_bias(const float* __restrict__ bmv, const float* __restrict__ bmg,
                           const float* __restrict__ brg, const float* __restrict__ bhw,
                           float* __restrict__ out) {
  const int i = blockIdx.x * 256 + threadIdx.x;     // 3072
  float v;
  if (i < 768) v = bmv[i];
  else if (i < 1536) v = bmg[i - 768];
  else if (i < 2304) v = brg[i - 1536];
  else v = bhw[i - 2304];
  out[i] = v;
}

// h_pad[t][d]: rows 0,1 = 0; row 2+t = emb[x[t]] + pos[t]. grid 2050 x 256
__global__ void embed_k(const int* __restrict__ x, const float* __restrict__ emb,
                        const float* __restrict__ pos, bf16_t* __restrict__ hpad) {
  const int t = blockIdx.x, tid = threadIdx.x;
  int id = 0, tt = t - 2;
  if (t >= 2) id = x[tt];
  #pragma unroll
  for (int q = 0; q < 3; ++q) {
    const int d = tid + q * 256;
    float v = 0.f;
    if (t >= 2) v = emb[(size_t)id * DD + d] + pos[(size_t)tt * DD + d];
    hpad[(size_t)t * DD + d] = __float2bfloat16(v);
  }
}

// one block per output row t. tmp row r=t-step: [val | gate | rg | hw] (3072 fp32)
__global__ __launch_bounds__(256) void merge_ew(
    const bf16_t* __restrict__ curOldB, const float* __restrict__ curOldF,
    bf16_t* __restrict__ curNewB, float* __restrict__ curNewF,
    const float* __restrict__ tmp, const float* __restrict__ rmsw, int step)
{
  const int t = blockIdx.x, tid = threadIdx.x;
  if (t < step) {  // passthrough rows
    const uint4* sF = (const uint4*)(curOldF + (size_t)t * DD);
    uint4* dF = (uint4*)(curNewF + (size_t)t * DD);
    if (tid < 192) dF[tid] = sF[tid];
    const uint4* sB = (const uint4*)(curOldB + (size_t)t * DD);
    uint4* dB = (uint4*)(curNewB + (size_t)t * DD);
    if (tid < 96) dB[tid] = sB[tid];
    return;
  }
  const int r = t - step;
  const float* row = tmp + (size_t)r * 3072;
  float mv[3]; float ss = 0.f;
  #pragma unroll
  for (int q = 0; q < 3; ++q) {
    const int d = tid + q * 256;
    const float m = row[d] * sigmoid_f(row[768 + d]);
    mv[q] = m; ss += m * m;
  }
  #pragma unroll
  for (int o = 32; o >= 1; o >>= 1) ss += __shfl_down(ss, o, 64);
  __shared__ float red[4];
  if ((tid & 63) == 0) red[tid >> 6] = ss;
  __syncthreads();
  const float tot = red[0] + red[1] + red[2] + red[3];
  const float scale = rsqrtf(tot * (1.f / 768.f) + 1.1920929e-07f);
  #pragma unroll
  for (int q = 0; q < 3; ++q) {
    const int d = tid + q * 256;
    float merged = mv[q] * scale * rmsw[d];
    const float right = curOldF[(size_t)t * DD + d];
    const float left  = curOldF[(size_t)r * DD + d];
    const float hg = sigmoid_f(row[2304 + d]);
    merged = hg * merged + (1.f - hg) * right;
    const float rg = sigmoid_f(row[1536 + d]);
    merged = rg * merged + (1.f - rg) * (left + right) * 0.5f;
    curNewF[(size_t)t * DD + d] = merged;
    curNewB[(size_t)t * DD + d] = __float2bfloat16(merged);
  }
}

extern "C" void kernel_launch(void* const* d_in, const int* in_sizes, int n_in,
                              void* d_out, int out_size, void* d_ws, size_t ws_size,
                              hipStream_t stream) {
  const int*   x      = (const int*)  d_in[0];
  const float* emb    = (const float*)d_in[1];
  const float* pos    = (const float*)d_in[2];
  const float* conv_w = (const float*)d_in[3];
  const float* conv_b = (const float*)d_in[4];
  const float* wg1    = (const float*)d_in[5];
  const float* bg1    = (const float*)d_in[6];
  const float* wmv    = (const float*)d_in[7];
  const float* bmv    = (const float*)d_in[8];
  const float* wmg    = (const float*)d_in[9];
  const float* bmg    = (const float*)d_in[10];
  const float* wrg    = (const float*)d_in[11];
  const float* brg    = (const float*)d_in[12];
  const float* whw    = (const float*)d_in[13];
  const float* bhw    = (const float*)d_in[14];
  const float* rmsw   = (const float*)d_in[15];
  const float* wpred  = (const float*)d_in[16];
  const float* bpred  = (const float*)d_in[17];

  char* ws = (char*)d_ws;
  size_t off = 0;
  auto carve = [&](size_t bytes) { char* p = ws + off; off += (bytes + 255) & ~(size_t)255; return p; };
  bf16_t* wpred_t  = (bf16_t*)carve(32000ull * 768 * 2);
  bf16_t* Wbig_t   = (bf16_t*)carve(3072ull * 1536 * 2);
  bf16_t* wc_t     = (bf16_t*)carve(768ull * 2304 * 2);
  bf16_t* wg1_t    = (bf16_t*)carve(768ull * 768 * 2);
  float*  bias_big = (float*) carve(3072 * 4);
  bf16_t* h_pad    = (bf16_t*)carve(2050ull * 768 * 2);
  float*  hconv    = (float*) carve(2048ull * 768 * 4);
  bf16_t* hconv_bf = (bf16_t*)carve(2048ull * 768 * 2);
  bf16_t* currA_b  = (bf16_t*)carve(2048ull * 768 * 2);
  bf16_t* currB_b  = (bf16_t*)carve(2048ull * 768 * 2);
  float*  currA_f  = (float*) carve(2048ull * 768 * 4);
  float*  currB_f  = (float*) carve(2048ull * 768 * 4);
  float*  tmp      = (float*) carve(2048ull * 3072 * 4);

  const dim3 tb(32, 8);
  // Wbig_t = [wmv | wmg | wrg | (0;whw)]^T  as [3072 n][1536 k]
  hipMemsetAsync(Wbig_t + 2304ull * 1536, 0, 768ull * 1536 * 2, stream);
  transpose_cvt<<<dim3(24, 48), tb, 0, stream>>>(wmv, Wbig_t,                      768, 1536);
  transpose_cvt<<<dim3(24, 48), tb, 0, stream>>>(wmg, Wbig_t + 768ull * 1536,      768, 1536);
  transpose_cvt<<<dim3(24, 48), tb, 0, stream>>>(wrg, Wbig_t + 1536ull * 1536,     768, 1536);
  transpose_cvt<<<dim3(24, 24), tb, 0, stream>>>(whw, Wbig_t + 2304ull * 1536 + 768, 768, 1536);
  transpose_cvt<<<dim3(24, 24), tb, 0, stream>>>(wg1, wg1_t, 768, 768);
  transpose_cvt<<<dim3(1000, 24), tb, 0, stream>>>(wpred, wpred_t, 32000, 768);
  build_wct<<<6912, 256, 0, stream>>>(conv_w, wc_t);
  build_bias<<<12, 256, 0, stream>>>(bmv, bmg, brg, bhw, bias_big);

  // h = embed + pos (2-row zero pad for causal conv)
  embed_k<<<2050, 256, 0, stream>>>(x, emb, pos, h_pad);

  // causal conv as shifted GEMM: K=2304, chunks -> h_pad rows t+0,t+1,t+2
  gemm_shift<<<96, 256, 0, stream>>>(h_pad, 768, 2048, 16, 0, 1, 2,
                                     wc_t, 2304, conv_b, hconv, 768, hconv_bf, nullptr);
  // curr0 = hconv * sigmoid(hconv @ wg1 + bg1)  (gate fused in epilogue)
  gemm_shift<<<96, 256, 0, stream>>>(hconv_bf, 768, 2048, 16, 0, 0, 0,
                                     wg1_t, 768, bg1, currA_f, 768, currA_b, hconv);

  bf16_t* curB = currA_b; float* curF = currA_f;
  bf16_t* nxtB = currB_b; float* nxtF = currB_f;
  for (int step = 1; step < 2048; step <<= 1) {
    const int M = 2048 - step;
    const int nRowT = (M + 127) / 128;
    gemm_shift<<<24 * nRowT, 256, 0, stream>>>(
        curB, 768, M, nRowT, 0, step, 0, Wbig_t, 1536, bias_big, tmp, 3072, nullptr, nullptr);
    merge_ew<<<2048, 256, 0, stream>>>(curB, curF, nxtB, nxtF, tmp, rmsw, step);
    { bf16_t* tb_ = curB; curB = nxtB; nxtB = tb_; }
    { float*  tf_ = curF; curF = nxtF; nxtF = tf_; }
  }

  // logits = curr @ wpred + bpred
  gemm_shift<<<250 * 16, 256, 0, stream>>>(curB, 768, 2048, 16, 0, 0, 0,
                                           wpred_t, 768, bpred, (float*)d_out, 32000, nullptr, nullptr);
}

// Round 4
// 953.547 us; speedup vs baseline: 1.1186x; 1.1186x over previous
//
#include <hip/hip_runtime.h>
#include <hip/hip_bf16.h>

typedef __attribute__((ext_vector_type(8))) short short8;
typedef __attribute__((ext_vector_type(4))) float floatx4;
typedef __hip_bfloat16 bf16_t;

#define DD 768

__device__ __forceinline__ float sigmoid_f(float x) { return 1.f / (1.f + __expf(-x)); }

__device__ __forceinline__ void gl2lds16(const void* g, void* l) {
  __builtin_amdgcn_global_load_lds((const __attribute__((address_space(1))) void*)g,
                                   (__attribute__((address_space(3))) void*)l, 16, 0, 0);
}

// ---------------------------------------------------------------------------
// 256x256-tile, BK=64, 512-thread (8 waves = 2M x 4N) bf16 MFMA GEMM with a
// 4-phase counted-vmcnt pipeline (T3+T4), slot-XOR LDS swizzle (T2), setprio
// (T5), bijective XCD swizzle (T1).
// Steady state: phase p stages one half-tile of tile t+1 and waits vmcnt(4).
// LAST tile: no stages are issued, so the queue stops advancing; the due
// half-tiles are now inside the newest-4 window. Per-phase drain {4,2,0,0}
// (phase1 needs A-h1 -> <=2 outstanding; phase2 needs B-h1 -> 0). This was
// the R3 race (nondeterministic last-K-tile quadrants).
// ---------------------------------------------------------------------------
__global__ __launch_bounds__(512, 2) void gemm256(
    const bf16_t* __restrict__ A, int lda, int M,
    const bf16_t* __restrict__ Wt, int wld, int Klen,
    int nRowT, int nColT,
    int shift0, int shift1, int koff0, int koff1,
    const float* __restrict__ bias0, const float* __restrict__ bias1,
    float* __restrict__ out0, float* __restrict__ out1, int N)
{
  __shared__ __attribute__((aligned(16))) unsigned char lds[131072];
  // A: [buf][256][64] bf16 at 0 + buf*32768 ; B: same at 65536 + buf*32768
  const int tid = threadIdx.x;
  const int wave = tid >> 6, lane = tid & 63;
  const int l15 = lane & 15, kq = lane >> 4;
  const int wm = wave >> 2, wn = wave & 3;

  // bijective XCD swizzle (m204)
  const int nwg = gridDim.x;
  const int q8 = nwg >> 3, r8 = nwg & 7;
  const int xcd = blockIdx.x & 7, lin = blockIdx.x >> 3;
  const int wgid = (xcd < r8 ? xcd * (q8 + 1) : r8 * (q8 + 1) + (xcd - r8) * q8) + lin;
  const int per = nRowT * nColT;
  const int ks = (wgid >= per) ? 1 : 0;
  const int w2 = wgid - ks * per;
  const int rowt = w2 % nRowT, colt = w2 / nRowT;
  const int shift = ks ? shift1 : shift0;
  const int koff  = ks ? koff1 : koff0;
  const float* bias = ks ? bias1 : bias0;
  float* out = ks ? out1 : out0;
  const int rowbase = rowt * 256, colbase = colt * 256;

  floatx4 acc[8][4] = {};
  const int nkt = Klen >> 6;

  auto stageA = [&](int mh, int kt, int buf) {
    const int kbase = kt << 6;
    #pragma unroll
    for (int rr = 0; rr < 2; ++rr) {
      const int L = rr * 64 + wave * 8;                       // wave-uniform
      const int lrow_base = (L >> 6) * 128 + mh * 64 + (L & 63);
      const int lrow = lrow_base + (lane >> 3);
      const int slotp = (lane & 7) ^ (lrow & 7);
      const int gr = min(rowbase + lrow, M - 1) + shift;
      gl2lds16(A + (size_t)gr * lda + kbase + slotp * 8,
               lds + buf * 32768 + lrow_base * 128);
    }
  };
  auto stageB = [&](int nh, int kt, int buf) {
    const int kbase = kt << 6;
    #pragma unroll
    for (int rr = 0; rr < 2; ++rr) {
      const int L = rr * 64 + wave * 8;
      const int lrow_base = (L >> 5) * 64 + nh * 32 + (L & 31);
      const int lrow = lrow_base + (lane >> 3);
      const int slotp = (lane & 7) ^ (lrow & 7);
      const int gn = colbase + lrow;
      gl2lds16(Wt + (size_t)gn * wld + koff + kbase + slotp * 8,
               lds + 65536 + buf * 32768 + lrow_base * 128);
    }
  };

  // prologue: stage tile 0 into buf 0
  stageA(0, 0, 0); stageB(0, 0, 0); stageA(1, 0, 0); stageB(1, 0, 0);

  int cur = 0;
  for (int t = 0; t < nkt; ++t) {
    const bool notlast = (t + 1 < nkt);
    #pragma unroll
    for (int p = 0; p < 4; ++p) {
      const int mh = p & 1, nh = p >> 1;
      if (notlast) {
        asm volatile("s_waitcnt vmcnt(4)" ::: "memory");
      } else if (p == 0) {
        asm volatile("s_waitcnt vmcnt(4)" ::: "memory");
      } else if (p == 1) {
        asm volatile("s_waitcnt vmcnt(2)" ::: "memory");
      } else {
        asm volatile("s_waitcnt vmcnt(0)" ::: "memory");
      }
      __builtin_amdgcn_s_barrier();

      const unsigned char* Ab = lds + cur * 32768;
      const unsigned char* Bb = lds + 65536 + cur * 32768;
      short8 av[4][2], bv[2][2];
      #pragma unroll
      for (int i = 0; i < 4; ++i) {
        const int r = wm * 128 + mh * 64 + i * 16 + l15;
        #pragma unroll
        for (int s = 0; s < 2; ++s) {
          const int slot = (s * 4 + kq) ^ (r & 7);
          av[i][s] = *reinterpret_cast<const short8*>(Ab + r * 128 + slot * 16);
        }
      }
      #pragma unroll
      for (int j = 0; j < 2; ++j) {
        const int r = wn * 64 + nh * 32 + j * 16 + l15;
        #pragma unroll
        for (int s = 0; s < 2; ++s) {
          const int slot = (s * 4 + kq) ^ (r & 7);
          bv[j][s] = *reinterpret_cast<const short8*>(Bb + r * 128 + slot * 16);
        }
      }
      if (notlast) {
        if (!(p & 1)) stageA(p >> 1, t + 1, cur ^ 1);
        else          stageB(p >> 1, t + 1, cur ^ 1);
      }
      __builtin_amdgcn_s_barrier();
      __builtin_amdgcn_s_setprio(1);
      #pragma unroll
      for (int i = 0; i < 4; ++i)
        #pragma unroll
        for (int j = 0; j < 2; ++j)
          #pragma unroll
          for (int s = 0; s < 2; ++s)
            acc[mh * 4 + i][nh * 2 + j] = __builtin_amdgcn_mfma_f32_16x16x32_bf16(
                av[i][s], bv[j][s], acc[mh * 4 + i][nh * 2 + j], 0, 0, 0);
      __builtin_amdgcn_s_setprio(0);
    }
    cur ^= 1;
  }

  // epilogue: C/D layout col=lane&15, row=(lane>>4)*4+reg
  const int hi = lane >> 4;
  #pragma unroll
  for (int i = 0; i < 8; ++i)
    #pragma unroll
    for (int j = 0; j < 4; ++j) {
      const int c = colbase + wn * 64 + j * 16 + l15;
      const float bb = bias ? bias[c] : 0.f;
      #pragma unroll
      for (int rg = 0; rg < 4; ++rg) {
        const int r = rowbase + wm * 128 + i * 16 + hi * 4 + rg;
        if (r < M) out[(size_t)r * N + c] = acc[i][j][rg] + bb;
      }
    }
}

// ---------------------------------------------------------------------------
// 128x128 2-phase GEMM (kept for conv + gate, which have N=768 -> small grids)
// ---------------------------------------------------------------------------
__global__ __launch_bounds__(256) void gemm_shift(
    const bf16_t* __restrict__ A, int lda, int M, int nRowT,
    int s0, int s1, int s2,
    const bf16_t* __restrict__ Wt, int Kdim,
    const float* __restrict__ bias,
    float* __restrict__ out, int N,
    bf16_t* __restrict__ out_bf,
    const float* __restrict__ gate_other)
{
  __shared__ __attribute__((aligned(16))) unsigned char lds[16384];
  const int tid  = threadIdx.x;
  const int wave = tid >> 6, lane = tid & 63;

  const int nwg = gridDim.x;
  const int q8 = nwg >> 3, r8 = nwg & 7;
  const int xcd = blockIdx.x & 7, lin = blockIdx.x >> 3;
  const int wgid = (xcd < r8 ? xcd * (q8 + 1) : r8 * (q8 + 1) + (xcd - r8) * q8) + lin;
  const int rowt = wgid % nRowT, colt = wgid / nRowT;

  const int rowbase = rowt * 128, colbase = colt * 128;
  const int wr = (wave >> 1) * 64, wc = (wave & 1) * 64;

  floatx4 acc[4][4] = {};
  const int nkt = Kdim >> 5;
  const int srow_t = tid >> 2;
  const int sslot  = tid & 3;

  for (int kt = 0; kt < nkt; ++kt) {
    const int kbase = kt << 5;
    const int chunk = kbase / 768;
    const int shift = (chunk == 0) ? s0 : ((chunk == 1) ? s1 : s2);
    const int csrc  = kbase - chunk * 768;

    __syncthreads();
    #pragma unroll
    for (int p = 0; p < 2; ++p) {
      const int row = p * 64 + srow_t;
      const int k8  = sslot ^ ((row >> 1) & 3);
      {
        const int gr = min(rowbase + row, M - 1) + shift;
        gl2lds16(A + (size_t)gr * lda + csrc + k8 * 8, lds + p * 4096 + wave * 1024);
      }
      {
        const int gn = colbase + row;
        gl2lds16(Wt + (size_t)gn * Kdim + kbase + k8 * 8, lds + 8192 + p * 4096 + wave * 1024);
      }
    }
    __syncthreads();

    const int l15 = lane & 15, kq = lane >> 4;
    short8 af[4], bfr[4];
    #pragma unroll
    for (int i = 0; i < 4; ++i) {
      const int arow = wr + i * 16 + l15;
      const int as   = kq ^ ((arow >> 1) & 3);
      af[i] = *reinterpret_cast<const short8*>(&lds[arow * 64 + as * 16]);
      const int brow = wc + i * 16 + l15;
      const int bs   = kq ^ ((brow >> 1) & 3);
      bfr[i] = *reinterpret_cast<const short8*>(&lds[8192 + brow * 64 + bs * 16]);
    }
    #pragma unroll
    for (int i = 0; i < 4; ++i)
      #pragma unroll
      for (int j = 0; j < 4; ++j)
        acc[i][j] = __builtin_amdgcn_mfma_f32_16x16x32_bf16(af[i], bfr[j], acc[i][j], 0, 0, 0);
  }

  const int l15 = lane & 15, hi = lane >> 4;
  #pragma unroll
  for (int i = 0; i < 4; ++i)
    #pragma unroll
    for (int j = 0; j < 4; ++j)
      #pragma unroll
      for (int rg = 0; rg < 4; ++rg) {
        const int r = rowbase + wr + i * 16 + hi * 4 + rg;
        const int c = colbase + wc + j * 16 + l15;
        if (r < M) {
          float v = acc[i][j][rg] + bias[c];
          if (gate_other) v = gate_other[(size_t)r * N + c] * sigmoid_f(v);
          out[(size_t)r * N + c] = v;
          if (out_bf) out_bf[(size_t)r * N + c] = __float2bfloat16(v);
        }
      }
}

__global__ void transpose_cvt(const float* __restrict__ in, bf16_t* __restrict__ out,
                              int in_ld, int out_ld)
{
  __shared__ float tile[32][33];
  const int n0 = blockIdx.x * 32, k0 = blockIdx.y * 32;
  const int tx = threadIdx.x, ty = threadIdx.y;
  #pragma unroll
  for (int yy = ty; yy < 32; yy += 8)
    tile[yy][tx] = in[(size_t)(k0 + yy) * in_ld + n0 + tx];
  __syncthreads();
  #pragma unroll
  for (int yy = ty; yy < 32; yy += 8)
    out[(size_t)(n0 + yy) * out_ld + k0 + tx] = __float2bfloat16(tile[tx][yy]);
}

__global__ void build_wct(const float* __restrict__ cw, bf16_t* __restrict__ wct) {
  const int idx = blockIdx.x * 256 + threadIdx.x;
  const int o = idx / 2304, c = idx - o * 2304;
  const int k = c / 768, i = c - k * 768;
  wct[idx] = __float2bfloat16(cw[o * 2304 + i * 3 + k]);
}

__global__ void build_bias(const float* __restrict__ bmv, const float* __restrict__ bmg,
                           const float* __restrict__ brg, const float* __restrict__ bhw,
                           float* __restrict__ out) {
  const int i = blockIdx.x * 256 + threadIdx.x;
  float v;
  if (i < 768) v = bmv[i];
  else if (i < 1536) v = bmg[i - 768];
  else if (i < 2304) v = brg[i - 1536];
  else v = bhw[i - 2304];
  out[i] = v;
}

__global__ void embed_k(const int* __restrict__ x, const float* __restrict__ emb,
                        const float* __restrict__ pos, bf16_t* __restrict__ hpad) {
  const int t = blockIdx.x, tid = threadIdx.x;
  int id = 0, tt = t - 2;
  if (t >= 2) id = x[tt];
  #pragma unroll
  for (int q = 0; q < 3; ++q) {
    const int d = tid + q * 256;
    float v = 0.f;
    if (t >= 2) v = emb[(size_t)id * DD + d] + pos[(size_t)tt * DD + d];
    hpad[(size_t)t * DD + d] = __float2bfloat16(v);
  }
}

// one block per output row t. tmp/tmp2 rows r: K-split halves, summed here.
__global__ __launch_bounds__(256) void merge_ew(
    const bf16_t* __restrict__ curOldB, const float* __restrict__ curOldF,
    bf16_t* __restrict__ curNewB, float* __restrict__ curNewF,
    const float* __restrict__ tmp, const float* __restrict__ tmp2,
    const float* __restrict__ rmsw, int step)
{
  const int t = blockIdx.x, tid = threadIdx.x;
  if (t < step) {
    const uint4* sF = (const uint4*)(curOldF + (size_t)t * DD);
    uint4* dF = (uint4*)(curNewF + (size_t)t * DD);
    if (tid < 192) dF[tid] = sF[tid];
    const uint4* sB = (const uint4*)(curOldB + (size_t)t * DD);
    uint4* dB = (uint4*)(curNewB + (size_t)t * DD);
    if (tid < 96) dB[tid] = sB[tid];
    return;
  }
  const int r = t - step;
  const float* row  = tmp  + (size_t)r * 3072;
  const float* row2 = tmp2 + (size_t)r * 3072;
  float mv[3]; float ss = 0.f;
  #pragma unroll
  for (int q = 0; q < 3; ++q) {
    const int d = tid + q * 256;
    const float m = (row[d] + row2[d]) * sigmoid_f(row[768 + d] + row2[768 + d]);
    mv[q] = m; ss += m * m;
  }
  #pragma unroll
  for (int o = 32; o >= 1; o >>= 1) ss += __shfl_down(ss, o, 64);
  __shared__ float red[4];
  if ((tid & 63) == 0) red[tid >> 6] = ss;
  __syncthreads();
  const float tot = red[0] + red[1] + red[2] + red[3];
  const float scale = rsqrtf(tot * (1.f / 768.f) + 1.1920929e-07f);
  #pragma unroll
  for (int q = 0; q < 3; ++q) {
    const int d = tid + q * 256;
    float merged = mv[q] * scale * rmsw[d];
    const float right = curOldF[(size_t)t * DD + d];
    const float left  = curOldF[(size_t)r * DD + d];
    const float hg = sigmoid_f(row[2304 + d] + row2[2304 + d]);
    merged = hg * merged + (1.f - hg) * right;
    const float rg = sigmoid_f(row[1536 + d] + row2[1536 + d]);
    merged = rg * merged + (1.f - rg) * (left + right) * 0.5f;
    curNewF[(size_t)t * DD + d] = merged;
    curNewB[(size_t)t * DD + d] = __float2bfloat16(merged);
  }
}

extern "C" void kernel_launch(void* const* d_in, const int* in_sizes, int n_in,
                              void* d_out, int out_size, void* d_ws, size_t ws_size,
                              hipStream_t stream) {
  const int*   x      = (const int*)  d_in[0];
  const float* emb    = (const float*)d_in[1];
  const float* pos    = (const float*)d_in[2];
  const float* conv_w = (const float*)d_in[3];
  const float* conv_b = (const float*)d_in[4];
  const float* wg1    = (const float*)d_in[5];
  const float* bg1    = (const float*)d_in[6];
  const float* wmv    = (const float*)d_in[7];
  const float* bmv    = (const float*)d_in[8];
  const float* wmg    = (const float*)d_in[9];
  const float* bmg    = (const float*)d_in[10];
  const float* wrg    = (const float*)d_in[11];
  const float* brg    = (const float*)d_in[12];
  const float* whw    = (const float*)d_in[13];
  const float* bhw    = (const float*)d_in[14];
  const float* rmsw   = (const float*)d_in[15];
  const float* wpred  = (const float*)d_in[16];
  const float* bpred  = (const float*)d_in[17];

  char* ws = (char*)d_ws;
  size_t off = 0;
  auto carve = [&](size_t bytes) { char* p = ws + off; off += (bytes + 255) & ~(size_t)255; return p; };
  bf16_t* wpred_t  = (bf16_t*)carve(32000ull * 768 * 2);
  bf16_t* Wbig_t   = (bf16_t*)carve(3072ull * 1536 * 2);
  bf16_t* wc_t     = (bf16_t*)carve(768ull * 2304 * 2);
  bf16_t* wg1_t    = (bf16_t*)carve(768ull * 768 * 2);
  float*  bias_big = (float*) carve(3072 * 4);
  bf16_t* h_pad    = (bf16_t*)carve(2050ull * 768 * 2);
  float*  hconv    = (float*) carve(2048ull * 768 * 4);
  bf16_t* hconv_bf = (bf16_t*)carve(2048ull * 768 * 2);
  bf16_t* currA_b  = (bf16_t*)carve(2048ull * 768 * 2);
  bf16_t* currB_b  = (bf16_t*)carve(2048ull * 768 * 2);
  float*  currA_f  = (float*) carve(2048ull * 768 * 4);
  float*  currB_f  = (float*) carve(2048ull * 768 * 4);
  float*  tmp      = (float*) carve(2048ull * 3072 * 4);
  float*  tmp2     = (float*)d_out;  // d_out (262 MB) is dead until final GEMM

  const dim3 tb(32, 8);
  hipMemsetAsync(Wbig_t + 2304ull * 1536, 0, 768ull * 1536 * 2, stream);
  transpose_cvt<<<dim3(24, 48), tb, 0, stream>>>(wmv, Wbig_t,                        768, 1536);
  transpose_cvt<<<dim3(24, 48), tb, 0, stream>>>(wmg, Wbig_t + 768ull * 1536,        768, 1536);
  transpose_cvt<<<dim3(24, 48), tb, 0, stream>>>(wrg, Wbig_t + 1536ull * 1536,       768, 1536);
  transpose_cvt<<<dim3(24, 24), tb, 0, stream>>>(whw, Wbig_t + 2304ull * 1536 + 768, 768, 1536);
  transpose_cvt<<<dim3(24, 24), tb, 0, stream>>>(wg1, wg1_t, 768, 768);
  transpose_cvt<<<dim3(1000, 24), tb, 0, stream>>>(wpred, wpred_t, 32000, 768);
  build_wct<<<6912, 256, 0, stream>>>(conv_w, wc_t);
  build_bias<<<12, 256, 0, stream>>>(bmv, bmg, brg, bhw, bias_big);

  embed_k<<<2050, 256, 0, stream>>>(x, emb, pos, h_pad);

  // causal conv as shifted GEMM (3 chunks of h_pad rows t+0,t+1,t+2)
  gemm_shift<<<96, 256, 0, stream>>>(h_pad, 768, 2048, 16, 0, 1, 2,
                                     wc_t, 2304, conv_b, hconv, 768, hconv_bf, nullptr);
  // curr0 = hconv * sigmoid(hconv @ wg1 + bg1)
  gemm_shift<<<96, 256, 0, stream>>>(hconv_bf, 768, 2048, 16, 0, 0, 0,
                                     wg1_t, 768, bg1, currA_f, 768, currA_b, hconv);

  bf16_t* curB = currA_b; float* curF = currA_f;
  bf16_t* nxtB = currB_b; float* nxtF = currB_f;
  for (int step = 1; step < 2048; step <<= 1) {
    const int M = 2048 - step;
    const int nRowT = (M + 255) / 256;
    // K-split merge GEMM: half0 = left (shift 0, k 0:768), half1 = right (shift step, k 768:1536)
    gemm256<<<2 * nRowT * 12, 512, 0, stream>>>(
        curB, 768, M, Wbig_t, 1536, 768, nRowT, 12,
        0, step, 0, 768, bias_big, nullptr, tmp, tmp2, 3072);
    merge_ew<<<2048, 256, 0, stream>>>(curB, curF, nxtB, nxtF, tmp, tmp2, rmsw, step);
    { bf16_t* tb_ = curB; curB = nxtB; nxtB = tb_; }
    { float*  tf_ = curF; curF = nxtF; nxtF = tf_; }
  }

  // logits = curr @ wpred + bpred
  gemm256<<<8 * 125, 512, 0, stream>>>(curB, 768, 2048, wpred_t, 768, 768, 8, 125,
                                       0, 0, 0, 0, bpred, nullptr, (float*)d_out, nullptr, 32000);
}